// Round 5
// baseline (234.064 us; speedup 1.0000x reference)
//
#include <hip/hip_runtime.h>
#include <cmath>
#include <utility>

// Sliding-window min over time, window W=64, per column (Van Herk / Gil-Werman).
// out[t][d] = min(signal[max(0,t-63)..t][d]).
//
// R5: fillBufferAligned in our own profile hits 6.75 TB/s at 9.6% occupancy ->
// occupancy/controller are not the wall; sequential streams are fine. Our
// kernel reads/writes 1 KB per row then jumps 32 KB -> ~zero DRAM page hits,
// ~54% effective DRAM efficiency (3.4 TB/s incl. L3-absorbed reads). This
// version widens each WG's contiguous footprint to 2 KB/row (THREADS=256 x
// float2), window state = 64x256 float2 = 128 KiB DYNAMIC LDS (static cap is
// 64 KiB; hipFuncSetAttribute once on host, not a stream op -> graph-safe).
// Grid 16x16 = 256 WGs = 1 WG/CU. CHUNK=32 doubles in-flight loads per wave
// (64 KB/CU) to cover loaded-latency, hedging the MLP theory.

constexpr int T_DIM = 4096;
constexpr int D_DIM = 8192;
constexpr int W = 64;            // window / block length
constexpr int TSEG = 256;        // time rows per workgroup (4 blocks of 64)
constexpr int NB = TSEG / W;     // 4
constexpr int CHUNK = 32;        // load-staging batch (32 loads in flight)
constexpr int NCH = W / CHUNK;   // 2
constexpr int THREADS = 256;
constexpr int PITCH2 = D_DIM / 2;  // row pitch in float2 units

typedef float v2f __attribute__((ext_vector_type(2)));

template <class F, int... Is>
__device__ __forceinline__ void unroll_seq(F&& f, std::integer_sequence<int, Is...>) {
    (f(std::integral_constant<int, Is>{}), ...);
}
template <int N, class F>
__device__ __forceinline__ void unroll(F&& f) {
    unroll_seq(static_cast<F&&>(f), std::make_integer_sequence<int, N>{});
}

__device__ __forceinline__ v2f vmin2(v2f a, v2f b) {
    v2f r;
    r[0] = fminf(a[0], b[0]);
    r[1] = fminf(a[1], b[1]);
    return r;
}

__global__ __launch_bounds__(THREADS, 1)
void TemporalOperator_74182675136668_kernel(const float* __restrict__ in,
                                            float* __restrict__ out) {
    // Window state: S[row*THREADS + tid], thread owns 2 adjacent columns.
    // 64 * 256 * 8 B = 128 KiB (dynamic). Row index wave-uniform -> banks
    // balanced for ds_*_b64, no conflicts (R3/R4 measured 0).
    extern __shared__ v2f S[];

    const int tid = threadIdx.x;
    const int col2 = blockIdx.x * THREADS + tid;   // float2-column index
    const int t0 = blockIdx.y * TSEG;              // segment start row
    const v2f* pin = (const v2f*)in + col2;
    v2f* pout = (v2f*)out + col2;

    if (t0 == 0) {
        v2f z; z[0] = INFINITY; z[1] = INFINITY;
#pragma unroll
        for (int i = 0; i < W; ++i) S[i * THREADS + tid] = z;
    } else {
        // Prime: stage the 64 rows preceding this segment, build suffix mins.
        const v2f* pp = pin + (t0 - W) * PITCH2;
#pragma unroll
        for (int c = 0; c < NCH; ++c) {
            v2f tmp[CHUNK];
            unroll<CHUNK>([&](auto J) { tmp[J] = pp[(c * CHUNK + J) * PITCH2]; });
            unroll<CHUNK>([&](auto J) { S[(c * CHUNK + J) * THREADS + tid] = tmp[J]; });
        }
        v2f s = S[(W - 1) * THREADS + tid];
#pragma unroll
        for (int i = W - 2; i >= 0; --i) {
            v2f x = S[i * THREADS + tid];
            s = vmin2(s, x);
            S[i * THREADS + tid] = s;
        }
    }

    // Main loop. S holds suffix-mins of the previous 64-block; consume S[i+1]
    // while overwriting slot i with the current block's raw value (slot i is
    // dead -- consumed on iteration i-1).
    v2f buf[2][CHUNK];  // compile-time-parity ping-pong, lives in VGPRs
    unroll<CHUNK>([&](auto J) { buf[0][J] = pin[(t0 + J) * PITCH2]; });

    for (int b = 0; b < NB; ++b) {
        const int tb = t0 + b * W;
        v2f L; L[0] = INFINITY; L[1] = INFINITY;  // running prefix min
        unroll<NCH>([&](auto C) {
            constexpr int p = C & 1;   // NCH=2: global batch parity == C
            // Prefetch the NEXT 32 rows (crosses into the next block at C==1:
            // parity p^1==0 matches next block's C==0 read buffer) BEFORE this
            // batch's stores, so load waits never drain store acks.
            const bool pf = (b * W + (C + 1) * CHUNK < TSEG);
            if (pf)
                unroll<CHUNK>([&](auto J) {
                    buf[p ^ 1][J] = pin[(tb + (C + 1) * CHUNK + J) * PITCH2];
                });
            unroll<CHUNK>([&](auto J) {
                constexpr int i = C * CHUNK + J;
                L = vmin2(L, buf[p][J]);
                // window [tb+i-63, tb+i] = prev rows [i+1..63] + cur rows [0..i]
                v2f o;
                if constexpr (i + 1 < W) o = vmin2(L, S[(i + 1) * THREADS + tid]);
                else                     o = L;
                __builtin_nontemporal_store(o, &pout[(tb + i) * PITCH2]);
                S[i * THREADS + tid] = buf[p][J];  // slot i consumed on iter i-1
            });
        });
        // Turn staged raw values into suffix mins for the next block.
        // (Next block's first 32 loads are already in flight.)
        if (b + 1 < NB) {
            v2f s = S[(W - 1) * THREADS + tid];
#pragma unroll
            for (int i = W - 2; i >= 0; --i) {
                v2f x = S[i * THREADS + tid];
                s = vmin2(s, x);
                S[i * THREADS + tid] = s;
            }
        }
    }
}

extern "C" void kernel_launch(void* const* d_in, const int* in_sizes, int n_in,
                              void* d_out, int out_size, void* d_ws, size_t ws_size,
                              hipStream_t stream) {
    const float* in = (const float*)d_in[0];
    float* out = (float*)d_out;
    constexpr size_t SHMEM = (size_t)W * THREADS * sizeof(v2f);  // 131072 B
    static bool inited = false;
    if (!inited) {
        hipFuncSetAttribute((const void*)TemporalOperator_74182675136668_kernel,
                            hipFuncAttributeMaxDynamicSharedMemorySize,
                            (int)SHMEM);
        inited = true;
    }
    dim3 grid(PITCH2 / THREADS, T_DIM / TSEG);  // 16 x 16 = 256 blocks, 1/CU
    TemporalOperator_74182675136668_kernel<<<grid, THREADS, SHMEM, stream>>>(in, out);
}